// Round 2
// baseline (6196.349 us; speedup 1.0000x reference)
//
#include <hip/hip_runtime.h>
#include <hip/hip_bf16.h>

#define D_MODEL 1024
#define N_HEADS 16
#define HEAD_DIM 64
#define BATCH 4
#define SEQ 2048
#define M_TOTAL (BATCH * SEQ)   // 8192 rows

// ---------------------------------------------------------------------------
// Y[M,N] = X[M,K] @ W[N,K]^T   (torch-style linear: y = x @ W^T)
// fp32 in/out, fp32 accumulate. Tiled: 64x64 block tile, BK=16,
// 256 threads, 4x4 outputs per thread.
// ---------------------------------------------------------------------------
__global__ __launch_bounds__(256) void gemm_bt(const float* __restrict__ X,
                                               const float* __restrict__ W,
                                               float* __restrict__ Y,
                                               int M, int N, int K) {
    __shared__ float Xs[64][17];
    __shared__ float Ws[64][17];

    const int tid = threadIdx.x;           // 0..255
    const int tr = tid >> 4;               // 0..15  (row group)
    const int tc = tid & 15;               // 0..15  (col group)
    const int rowBase = blockIdx.y * 64;
    const int colBase = blockIdx.x * 64;

    float c[4][4];
#pragma unroll
    for (int i = 0; i < 4; ++i)
#pragma unroll
        for (int j = 0; j < 4; ++j) c[i][j] = 0.f;

    for (int k0 = 0; k0 < K; k0 += 16) {
        // load 64x16 tiles of X and W into LDS (4 elems each per thread)
#pragma unroll
        for (int l = 0; l < 4; ++l) {
            int idx = tid + l * 256;       // 0..1023
            int r = idx >> 4;              // 0..63
            int kk = idx & 15;             // 0..15
            Xs[r][kk] = X[(size_t)(rowBase + r) * K + k0 + kk];
            Ws[r][kk] = W[(size_t)(colBase + r) * K + k0 + kk];
        }
        __syncthreads();

#pragma unroll
        for (int kk = 0; kk < 16; ++kk) {
            float a[4], b[4];
#pragma unroll
            for (int i = 0; i < 4; ++i) a[i] = Xs[tr * 4 + i][kk];
#pragma unroll
            for (int j = 0; j < 4; ++j) b[j] = Ws[tc * 4 + j][kk];
#pragma unroll
            for (int i = 0; i < 4; ++i)
#pragma unroll
                for (int j = 0; j < 4; ++j) c[i][j] += a[i] * b[j];
        }
        __syncthreads();
    }

#pragma unroll
    for (int i = 0; i < 4; ++i) {
        int row = rowBase + tr * 4 + i;
#pragma unroll
        for (int j = 0; j < 4; ++j) {
            int col = colBase + tc * 4 + j;
            Y[(size_t)row * N + col] = c[i][j];
        }
    }
}

// ---------------------------------------------------------------------------
// Attention: one wave (64 threads) per (b, h, q_row).
// Q/K/V layout: (B*S, D) with head h occupying columns [h*64, h*64+64).
// Causal + key-padding mask, scale = 1/sqrt(64) = 0.125.
// CTX may alias Q: each block reads only its own 64-element Q slice (at the
// start) and overwrites exactly that slice at the end; no cross-block sharing.
// ---------------------------------------------------------------------------
__global__ __launch_bounds__(64) void attn(const float* __restrict__ Q,
                                           const float* __restrict__ K,
                                           const float* __restrict__ V,
                                           const int* __restrict__ mask,
                                           float* __restrict__ CTX) {
    const int bid = blockIdx.x;            // 0 .. B*H*S-1
    const int qi = bid % SEQ;
    const int bh = bid / SEQ;
    const int h = bh % N_HEADS;
    const int b = bh / N_HEADS;
    const int lane = threadIdx.x;          // 0..63

    __shared__ float qs[HEAD_DIM];
    __shared__ float ps[SEQ];

    const size_t base = (size_t)b * SEQ * D_MODEL + (size_t)h * HEAD_DIM;

    qs[lane] = Q[base + (size_t)qi * D_MODEL + lane];
    __syncthreads();

    // ---- phase 1: raw scores into LDS, track max --------------------------
    float smax = -INFINITY;
    for (int i = 0; i < 32; ++i) {
        int j = i * 64 + lane;
        if (i * 64 > qi) break;            // wave-uniform early exit
        float s = -INFINITY;
        if (j <= qi && mask[b * SEQ + j] != 0) {
            const float* krow = K + base + (size_t)j * D_MODEL;
            float acc = 0.f;
#pragma unroll
            for (int d = 0; d < HEAD_DIM; ++d) acc += qs[d] * krow[d];
            s = acc * 0.125f;
        }
        ps[j] = s;
        smax = fmaxf(smax, s);
    }
#pragma unroll
    for (int off = 32; off > 0; off >>= 1)
        smax = fmaxf(smax, __shfl_xor(smax, off));
    __syncthreads();

    // ---- phase 2: exponentiate, sum -------------------------------------
    float lsum = 0.f;
    for (int i = 0; i < 32; ++i) {
        int j = i * 64 + lane;
        if (i * 64 > qi) break;
        if (j <= qi) {
            float s = ps[j];
            float p = (s > -INFINITY) ? __expf(s - smax) : 0.f;
            ps[j] = p;
            lsum += p;
        }
    }
#pragma unroll
    for (int off = 32; off > 0; off >>= 1) lsum += __shfl_xor(lsum, off);
    __syncthreads();

    const float inv = 1.f / lsum;

    // ---- phase 3: O = P @ V, lane = output dim ---------------------------
    float acc = 0.f;
    for (int j = 0; j <= qi; ++j) {
        float p = ps[j];                                   // LDS broadcast
        acc += p * V[base + (size_t)j * D_MODEL + lane];   // coalesced
    }
    CTX[base + (size_t)qi * D_MODEL + lane] = acc * inv;
}

// ---------------------------------------------------------------------------
extern "C" void kernel_launch(void* const* d_in, const int* in_sizes, int n_in,
                              void* d_out, int out_size, void* d_ws, size_t ws_size,
                              hipStream_t stream) {
    const float* x  = (const float*)d_in[0];
    const int* mask = (const int*)d_in[1];
    const float* wq = (const float*)d_in[2];
    const float* wk = (const float*)d_in[3];
    const float* wv = (const float*)d_in[4];
    const float* wo = (const float*)d_in[5];
    float* out = (float*)d_out;

    const size_t rowElems = (size_t)M_TOTAL * D_MODEL;   // 8192*1024
    float* Q   = (float*)d_ws;
    float* Kb  = Q + rowElems;
    float* Vb  = Kb + rowElems;
    float* CTX = Q;                       // alias: safe (see attn comment)

    dim3 gblock(256);
    dim3 ggrid(D_MODEL / 64, M_TOTAL / 64);   // (16, 128)

    gemm_bt<<<ggrid, gblock, 0, stream>>>(x, wq, Q,  M_TOTAL, D_MODEL, D_MODEL);
    gemm_bt<<<ggrid, gblock, 0, stream>>>(x, wk, Kb, M_TOTAL, D_MODEL, D_MODEL);
    gemm_bt<<<ggrid, gblock, 0, stream>>>(x, wv, Vb, M_TOTAL, D_MODEL, D_MODEL);

    dim3 ablock(64);
    dim3 agrid(BATCH * N_HEADS * SEQ);        // 131072 waves
    attn<<<agrid, ablock, 0, stream>>>(Q, Kb, Vb, mask, CTX);

    gemm_bt<<<ggrid, gblock, 0, stream>>>(CTX, wo, out, M_TOTAL, D_MODEL, D_MODEL);
}

// Round 3
// 5303.193 us; speedup vs baseline: 1.1684x; 1.1684x over previous
//
#include <hip/hip_runtime.h>
#include <hip/hip_bf16.h>

#define D_MODEL 1024
#define N_HEADS 16
#define HEAD_DIM 64
#define BATCH 4
#define SEQ 2048
#define M_TOTAL (BATCH * SEQ)   // 8192 rows

// ---------------------------------------------------------------------------
// Y[M,N] = X[M,K] @ W[N,K]^T   (torch-style linear: y = x @ W^T)
// fp32 in/out, fp32 accumulate. 64x64 block tile, BK=16, 256 threads,
// 4x4 outputs per thread.
// ---------------------------------------------------------------------------
__global__ __launch_bounds__(256) void gemm_bt(const float* __restrict__ X,
                                               const float* __restrict__ W,
                                               float* __restrict__ Y,
                                               int M, int N, int K) {
    __shared__ float Xs[64][17];
    __shared__ float Ws[64][17];

    const int tid = threadIdx.x;
    const int tr = tid >> 4;
    const int tc = tid & 15;
    const int rowBase = blockIdx.y * 64;
    const int colBase = blockIdx.x * 64;

    float c[4][4];
#pragma unroll
    for (int i = 0; i < 4; ++i)
#pragma unroll
        for (int j = 0; j < 4; ++j) c[i][j] = 0.f;

    for (int k0 = 0; k0 < K; k0 += 16) {
#pragma unroll
        for (int l = 0; l < 4; ++l) {
            int idx = tid + l * 256;
            int r = idx >> 4;
            int kk = idx & 15;
            Xs[r][kk] = X[(size_t)(rowBase + r) * K + k0 + kk];
            Ws[r][kk] = W[(size_t)(colBase + r) * K + k0 + kk];
        }
        __syncthreads();

#pragma unroll
        for (int kk = 0; kk < 16; ++kk) {
            float a[4], b[4];
#pragma unroll
            for (int i = 0; i < 4; ++i) a[i] = Xs[tr * 4 + i][kk];
#pragma unroll
            for (int j = 0; j < 4; ++j) b[j] = Ws[tc * 4 + j][kk];
#pragma unroll
            for (int i = 0; i < 4; ++i)
#pragma unroll
                for (int j = 0; j < 4; ++j) c[i][j] += a[i] * b[j];
        }
        __syncthreads();
    }

#pragma unroll
    for (int i = 0; i < 4; ++i) {
        int row = rowBase + tr * 4 + i;
#pragma unroll
        for (int j = 0; j < 4; ++j) {
            int col = colBase + tc * 4 + j;
            Y[(size_t)row * N + col] = c[i][j];
        }
    }
}

// ---------------------------------------------------------------------------
// Flash attention: one 256-thread block per (b, h, 64-row q tile).
// Thread (tq = tid>>4, tk = tid&15) owns q-rows {tq+16r} and k-cols/dims
// {tk+16c} (interleaved mapping -> all hot LDS b128 reads are <=2-way
// bank-aliased, which is free on gfx950).
// LDS: Qs,Ks,Vs at 64x68 fp32; P tile reuses Ks after scores are consumed.
// CTX may alias Q (block reads only its own Q tile before writing it).
// ---------------------------------------------------------------------------
__global__ __launch_bounds__(256) void flash_attn(const float* __restrict__ Q,
                                                  const float* __restrict__ K,
                                                  const float* __restrict__ V,
                                                  const int* __restrict__ mask,
                                                  float* __restrict__ CTX) {
    const int qt = blockIdx.x;             // 0..31
    const int bh = blockIdx.y;             // 0..63
    const int h = bh & (N_HEADS - 1);
    const int b = bh >> 4;
    const int tid = threadIdx.x;
    const int tq = tid >> 4;               // 0..15
    const int tk = tid & 15;               // 0..15
    const int q0 = qt * 64;

    __shared__ float Qs[64][68];
    __shared__ float Ks[64][68];           // later reused for P
    __shared__ float Vs[64][68];
    __shared__ float msks[64];

    const size_t base = (size_t)b * SEQ * D_MODEL + (size_t)h * HEAD_DIM;

    // ---- stage Q tile (pre-scaled by 1/sqrt(64)) -------------------------
    {
        const int r0 = tid >> 4;           // 0..15
        const int c4 = tid & 15;           // float4 col index
#pragma unroll
        for (int rr = 0; rr < 4; ++rr) {
            int r = r0 + 16 * rr;
            float4 q4 = *(const float4*)(Q + base + (size_t)(q0 + r) * D_MODEL + c4 * 4);
            q4.x *= 0.125f; q4.y *= 0.125f; q4.z *= 0.125f; q4.w *= 0.125f;
            *(float4*)&Qs[r][c4 * 4] = q4;
        }
    }

    float m[4], l[4], o[4][4];
#pragma unroll
    for (int r = 0; r < 4; ++r) {
        m[r] = -INFINITY;
        l[r] = 0.f;
#pragma unroll
        for (int c = 0; c < 4; ++c) o[r][c] = 0.f;
    }

    const int ntiles = qt + 1;             // causal: k-tiles 0..qt
    for (int t = 0; t < ntiles; ++t) {
        const int k0 = t * 64;
        __syncthreads();                   // prior iter done reading Ks/Vs (and Qs staged)

        // ---- stage K, V tiles + mask ------------------------------------
        {
            const int r0 = tid >> 4;
            const int c4 = tid & 15;
#pragma unroll
            for (int rr = 0; rr < 4; ++rr) {
                int r = r0 + 16 * rr;
                *(float4*)&Ks[r][c4 * 4] =
                    *(const float4*)(K + base + (size_t)(k0 + r) * D_MODEL + c4 * 4);
                *(float4*)&Vs[r][c4 * 4] =
                    *(const float4*)(V + base + (size_t)(k0 + r) * D_MODEL + c4 * 4);
            }
            if (tid < 64) msks[tid] = (float)mask[b * SEQ + k0 + tid];
        }
        __syncthreads();

        // ---- scores: S = (Q*scale) @ K^T, 4x4 per thread ----------------
        float s[4][4];
#pragma unroll
        for (int r = 0; r < 4; ++r)
#pragma unroll
            for (int c = 0; c < 4; ++c) s[r][c] = 0.f;

#pragma unroll
        for (int d4 = 0; d4 < 16; ++d4) {
            float a[4][4], bb[4][4];
#pragma unroll
            for (int r = 0; r < 4; ++r) {
                float4 t4 = *(const float4*)&Qs[tq + 16 * r][d4 * 4];
                a[r][0] = t4.x; a[r][1] = t4.y; a[r][2] = t4.z; a[r][3] = t4.w;
            }
#pragma unroll
            for (int c = 0; c < 4; ++c) {
                float4 t4 = *(const float4*)&Ks[tk + 16 * c][d4 * 4];
                bb[c][0] = t4.x; bb[c][1] = t4.y; bb[c][2] = t4.z; bb[c][3] = t4.w;
            }
#pragma unroll
            for (int r = 0; r < 4; ++r)
#pragma unroll
                for (int c = 0; c < 4; ++c)
#pragma unroll
                    for (int u = 0; u < 4; ++u) s[r][c] += a[r][u] * bb[c][u];
        }

        // ---- mask + online softmax (registers + 16-lane shuffles) -------
        float p[4][4];
#pragma unroll
        for (int r = 0; r < 4; ++r) {
            const int i = q0 + tq + 16 * r;          // global q index
            float rm = -INFINITY;
#pragma unroll
            for (int c = 0; c < 4; ++c) {
                const int j = k0 + tk + 16 * c;      // global k index
                const bool valid = (j <= i) && (msks[tk + 16 * c] != 0.f);
                s[r][c] = valid ? s[r][c] : -INFINITY;
                rm = fmaxf(rm, s[r][c]);
            }
#pragma unroll
            for (int off = 1; off < 16; off <<= 1)
                rm = fmaxf(rm, __shfl_xor(rm, off));
            const float mn = fmaxf(m[r], rm);
            const float alpha = (m[r] > -INFINITY) ? __expf(m[r] - mn) : 0.f;
            float rs = 0.f;
#pragma unroll
            for (int c = 0; c < 4; ++c) {
                const float pv = (s[r][c] > -INFINITY) ? __expf(s[r][c] - mn) : 0.f;
                p[r][c] = pv;
                rs += pv;
            }
#pragma unroll
            for (int off = 1; off < 16; off <<= 1) rs += __shfl_xor(rs, off);
            l[r] = l[r] * alpha + rs;
            m[r] = mn;
#pragma unroll
            for (int c = 0; c < 4; ++c) o[r][c] *= alpha;
        }

        __syncthreads();                   // all threads done reading Ks as K

        // ---- write P into Ks (reused as P tile) -------------------------
#pragma unroll
        for (int r = 0; r < 4; ++r)
#pragma unroll
            for (int c = 0; c < 4; ++c)
                Ks[tq + 16 * r][tk + 16 * c] = p[r][c];
        __syncthreads();

        // ---- O += P @ V --------------------------------------------------
#pragma unroll
        for (int k4 = 0; k4 < 16; ++k4) {
            float pr[4][4];
#pragma unroll
            for (int r = 0; r < 4; ++r) {
                float4 t4 = *(const float4*)&Ks[tq + 16 * r][k4 * 4];
                pr[r][0] = t4.x; pr[r][1] = t4.y; pr[r][2] = t4.z; pr[r][3] = t4.w;
            }
#pragma unroll
            for (int u = 0; u < 4; ++u) {
                float vu[4];
#pragma unroll
                for (int c = 0; c < 4; ++c) vu[c] = Vs[k4 * 4 + u][tk + 16 * c];
#pragma unroll
                for (int r = 0; r < 4; ++r)
#pragma unroll
                    for (int c = 0; c < 4; ++c) o[r][c] += pr[r][u] * vu[c];
            }
        }
    }

    // ---- epilogue: normalize + store ------------------------------------
#pragma unroll
    for (int r = 0; r < 4; ++r) {
        const float inv = 1.f / l[r];
        const int i = q0 + tq + 16 * r;
#pragma unroll
        for (int c = 0; c < 4; ++c)
            CTX[base + (size_t)i * D_MODEL + tk + 16 * c] = o[r][c] * inv;
    }
}

// ---------------------------------------------------------------------------
extern "C" void kernel_launch(void* const* d_in, const int* in_sizes, int n_in,
                              void* d_out, int out_size, void* d_ws, size_t ws_size,
                              hipStream_t stream) {
    const float* x  = (const float*)d_in[0];
    const int* mask = (const int*)d_in[1];
    const float* wq = (const float*)d_in[2];
    const float* wk = (const float*)d_in[3];
    const float* wv = (const float*)d_in[4];
    const float* wo = (const float*)d_in[5];
    float* out = (float*)d_out;

    const size_t rowElems = (size_t)M_TOTAL * D_MODEL;
    float* Q   = (float*)d_ws;
    float* Kb  = Q + rowElems;
    float* Vb  = Kb + rowElems;
    float* CTX = Q;                        // alias: safe (see flash_attn comment)

    dim3 gblock(256);
    dim3 ggrid(D_MODEL / 64, M_TOTAL / 64);   // (16, 128)

    gemm_bt<<<ggrid, gblock, 0, stream>>>(x, wq, Q,  M_TOTAL, D_MODEL, D_MODEL);
    gemm_bt<<<ggrid, gblock, 0, stream>>>(x, wk, Kb, M_TOTAL, D_MODEL, D_MODEL);
    gemm_bt<<<ggrid, gblock, 0, stream>>>(x, wv, Vb, M_TOTAL, D_MODEL, D_MODEL);

    dim3 ablock(256);
    dim3 agrid(SEQ / 64, BATCH * N_HEADS);    // (32, 64)
    flash_attn<<<agrid, ablock, 0, stream>>>(Q, Kb, Vb, mask, CTX);

    gemm_bt<<<ggrid, gblock, 0, stream>>>(CTX, wo, out, M_TOTAL, D_MODEL, D_MODEL);
}

// Round 4
// 453.139 us; speedup vs baseline: 13.6743x; 11.7032x over previous
//
#include <hip/hip_runtime.h>
#include <cstdint>
#include <cstddef>

#define D_MODEL 1024
#define N_HEADS 16
#define HEAD_DIM 64
#define BATCH 4
#define SEQ 2048
#define M_TOTAL (BATCH * SEQ)   // 8192

typedef __attribute__((ext_vector_type(8))) short bf16x8;   // 8 bf16 = 4 VGPRs
typedef __attribute__((ext_vector_type(4))) float f32x4;

__device__ __forceinline__ unsigned short f2bu(float f) {
    union { float f; unsigned u; } x; x.f = f;
    unsigned r = x.u + 0x7FFFu + ((x.u >> 16) & 1u);   // RNE
    return (unsigned short)(r >> 16);
}

__device__ __forceinline__ void async16(void* lds, const void* g) {
    __builtin_amdgcn_global_load_lds(
        (const __attribute__((address_space(1))) void*)g,
        (__attribute__((address_space(3))) void*)lds, 16, 0, 0);
}

// ---------------------------------------------------------------------------
// fp32 -> bf16 cast, 4 elems/thread
// ---------------------------------------------------------------------------
__global__ __launch_bounds__(256) void cast_bf16(const float* __restrict__ src,
                                                 unsigned short* __restrict__ dst,
                                                 int n4) {
    int i = blockIdx.x * 256 + threadIdx.x;
    if (i >= n4) return;
    float4 v = ((const float4*)src)[i];
    ushort4 o;
    o.x = f2bu(v.x); o.y = f2bu(v.y); o.z = f2bu(v.z); o.w = f2bu(v.w);
    ((ushort4*)dst)[i] = o;
}

// ---------------------------------------------------------------------------
// Y[M,N] = X[M,K] @ W[N,K]^T, bf16 in, fp32 acc, OutT out (bf16 bits or f32).
// 128x128 tile, BK=32, 256 thr (4 waves, 2x2), 16x16x32 bf16 MFMA.
// LDS chunk XOR swizzle: slot = cc ^ ((row>>1)&3) -> frag reads 2-way max.
// ---------------------------------------------------------------------------
template <typename OutT>
__global__ __launch_bounds__(256) void gemm_bt_mfma(const unsigned short* __restrict__ X,
                                                    const unsigned short* __restrict__ W,
                                                    OutT* __restrict__ Y,
                                                    int M, int N, int K) {
    __shared__ short As[128 * 32];
    __shared__ short Bs[128 * 32];

    const int tid = threadIdx.x;
    const int w = tid >> 6;
    const int lane = tid & 63;
    const int quad = lane >> 4;
    const int l15 = lane & 15;
    const int wm = w & 1, wn = w >> 1;
    const int rowBase = blockIdx.y * 128;
    const int colBase = blockIdx.x * 128;

    f32x4 acc[4][4];
#pragma unroll
    for (int mi = 0; mi < 4; ++mi)
#pragma unroll
        for (int ni = 0; ni < 4; ++ni)
#pragma unroll
            for (int e = 0; e < 4; ++e) acc[mi][ni][e] = 0.f;

    for (int k0 = 0; k0 < K; k0 += 32) {
        __syncthreads();                       // prev iter frag reads done
#pragma unroll
        for (int l = 0; l < 2; ++l) {
            int c = tid + l * 256;             // chunk of 8 bf16
            int row = c >> 2, ccs = c & 3;
            int cc = ccs ^ ((row >> 1) & 3);   // logical k-chunk for this slot
            async16((char*)As + c * 16, X + (size_t)(rowBase + row) * K + k0 + cc * 8);
            async16((char*)Bs + c * 16, W + (size_t)(colBase + row) * K + k0 + cc * 8);
        }
        __syncthreads();                       // staging visible (vmcnt drained)

        bf16x8 a[4], b[4];
#pragma unroll
        for (int mi = 0; mi < 4; ++mi) {
            int r = wm * 64 + mi * 16 + l15;
            int slot = quad ^ ((r >> 1) & 3);
            a[mi] = *(const bf16x8*)&As[r * 32 + slot * 8];
        }
#pragma unroll
        for (int ni = 0; ni < 4; ++ni) {
            int r = wn * 64 + ni * 16 + l15;
            int slot = quad ^ ((r >> 1) & 3);
            b[ni] = *(const bf16x8*)&Bs[r * 32 + slot * 8];
        }
#pragma unroll
        for (int mi = 0; mi < 4; ++mi)
#pragma unroll
            for (int ni = 0; ni < 4; ++ni)
                acc[mi][ni] = __builtin_amdgcn_mfma_f32_16x16x32_bf16(a[mi], b[ni], acc[mi][ni], 0, 0, 0);
    }

    // C/D layout: col = lane&15, row = quad*4+reg
#pragma unroll
    for (int mi = 0; mi < 4; ++mi)
#pragma unroll
        for (int ni = 0; ni < 4; ++ni)
#pragma unroll
            for (int reg = 0; reg < 4; ++reg) {
                int row = rowBase + wm * 64 + mi * 16 + quad * 4 + reg;
                int col = colBase + wn * 64 + ni * 16 + l15;
                float v = acc[mi][ni][reg];
                if constexpr (sizeof(OutT) == 2) Y[(size_t)row * N + col] = (OutT)f2bu(v);
                else                             Y[(size_t)row * N + col] = v;
            }
}

// ---------------------------------------------------------------------------
// V[B*S, D] (head-sliced) -> Vt[bh][d][s]  (so PV B-frags read contiguous)
// ---------------------------------------------------------------------------
__global__ __launch_bounds__(256) void transpose_v(const unsigned short* __restrict__ V,
                                                   unsigned short* __restrict__ Vt) {
    const int st = blockIdx.x;     // key tile
    const int bh = blockIdx.y;
    const int b = bh >> 4, h = bh & 15;
    const int tid = threadIdx.x;
    const int s0 = st * 64;
    __shared__ unsigned short Ts[64 * 72];

#pragma unroll
    for (int l = 0; l < 2; ++l) {
        int c = tid + l * 256;
        int s = c >> 3, cc = c & 7;
        *(uint4*)&Ts[s * 72 + cc * 8] =
            *(const uint4*)&V[(size_t)(b * SEQ + s0 + s) * D_MODEL + h * HEAD_DIM + cc * 8];
    }
    __syncthreads();
#pragma unroll
    for (int l = 0; l < 2; ++l) {
        int c = tid + l * 256;
        int d = c >> 3, sc = c & 7;
        unsigned short tmp[8];
#pragma unroll
        for (int j = 0; j < 8; ++j) tmp[j] = Ts[(sc * 8 + j) * 72 + d];
        *(uint4*)&Vt[((size_t)bh * HEAD_DIM + d) * SEQ + s0 + sc * 8] = *(uint4*)tmp;
    }
}

// ---------------------------------------------------------------------------
// MFMA flash attention. Block = 256 thr (4 waves), 64-row q-tile, wave w owns
// rows w*16..+16. K-tiles of 64 keys. Causal + key-padding mask.
// Q frags persist in regs; S/O in MFMA C-layout (col=lane&15,row=quad*4+reg);
// P transits per-wave LDS (C-layout -> A-layout A[m=lane&15][k=quad*8+j]).
// Ks/Vs staged via global_load_lds with slot = cc ^ (row&7) swizzle (2-way max).
// CTX may alias the V buffer (flash reads Vt, not V).
// ---------------------------------------------------------------------------
__global__ __launch_bounds__(256) void flash_mfma(const unsigned short* __restrict__ Q,
                                                  const unsigned short* __restrict__ K,
                                                  const unsigned short* __restrict__ Vt,
                                                  const int* __restrict__ mask,
                                                  unsigned short* __restrict__ CTX) {
    __shared__ short Qs[64 * 64];
    __shared__ short Ks[64 * 64];
    __shared__ short Vs[64 * 64];
    __shared__ short Ps[4][16 * 72];           // per-wave, pitch 72 (144B, 16B-aligned)
    __shared__ int msk[64];

    const int qt = (int)(gridDim.x - 1) - (int)blockIdx.x;  // longest blocks first
    const int bh = blockIdx.y;
    const int b = bh >> 4, h = bh & 15;
    const int tid = threadIdx.x;
    const int w = tid >> 6, lane = tid & 63, quad = lane >> 4, l15 = lane & 15;
    const int q0 = qt * 64;

    const size_t qkBase = (size_t)b * SEQ * D_MODEL + (size_t)h * HEAD_DIM;
    const size_t vtBase = (size_t)bh * HEAD_DIM * SEQ;

    // ---- stage Q tile (identity layout; read once) -----------------------
#pragma unroll
    for (int l = 0; l < 2; ++l) {
        int c = tid + l * 256;
        int row = c >> 3, cc = c & 7;
        async16((char*)Qs + c * 16, Q + qkBase + (size_t)(q0 + row) * D_MODEL + cc * 8);
    }
    __syncthreads();

    bf16x8 qa[2];
#pragma unroll
    for (int ks = 0; ks < 2; ++ks)
        qa[ks] = *(const bf16x8*)&Qs[(w * 16 + l15) * 64 + ks * 32 + quad * 8];

    float mrow[4], lrow[4];
    f32x4 oacc[4];
#pragma unroll
    for (int r = 0; r < 4; ++r) {
        mrow[r] = -INFINITY; lrow[r] = 0.f;
#pragma unroll
        for (int e = 0; e < 4; ++e) oacc[r][e] = 0.f;
    }

    const int ntile_cnt = qt + 1;              // causal
    for (int t = 0; t < ntile_cnt; ++t) {
        const int k0 = t * 64;
        __syncthreads();                       // prev tile's Ks/Vs reads done
#pragma unroll
        for (int l = 0; l < 2; ++l) {
            int c = tid + l * 256;
            int row = c >> 3, ccs = c & 7;
            int cc = ccs ^ (row & 7);
            async16((char*)Ks + c * 16, K + qkBase + (size_t)(k0 + row) * D_MODEL + cc * 8);
            async16((char*)Vs + c * 16, Vt + vtBase + (size_t)row * SEQ + k0 + cc * 8);
        }
        if (tid < 64) msk[tid] = mask[b * SEQ + k0 + tid];
        __syncthreads();                       // staging visible

        // ---- S = Q K^T (8 MFMAs) ----------------------------------------
        f32x4 s[4];
#pragma unroll
        for (int nt = 0; nt < 4; ++nt)
#pragma unroll
            for (int e = 0; e < 4; ++e) s[nt][e] = 0.f;
#pragma unroll
        for (int ks = 0; ks < 2; ++ks)
#pragma unroll
            for (int nt = 0; nt < 4; ++nt) {
                int r = nt * 16 + l15;
                int slot = (ks * 4 + quad) ^ (r & 7);
                bf16x8 kb = *(const bf16x8*)&Ks[r * 64 + slot * 8];
                s[nt] = __builtin_amdgcn_mfma_f32_16x16x32_bf16(qa[ks], kb, s[nt], 0, 0, 0);
            }

        // ---- mask + online softmax --------------------------------------
        float p[4][4];
        int mok[4];
#pragma unroll
        for (int nt = 0; nt < 4; ++nt) mok[nt] = msk[nt * 16 + l15];
#pragma unroll
        for (int reg = 0; reg < 4; ++reg) {
            const int i = q0 + w * 16 + quad * 4 + reg;
            float sv[4];
            float rm = -INFINITY;
#pragma unroll
            for (int nt = 0; nt < 4; ++nt) {
                int j = k0 + nt * 16 + l15;
                float v = s[nt][reg] * 0.125f;
                bool valid = (mok[nt] != 0) && (j <= i);
                sv[nt] = valid ? v : -INFINITY;
                rm = fmaxf(rm, sv[nt]);
            }
#pragma unroll
            for (int off = 1; off < 16; off <<= 1)
                rm = fmaxf(rm, __shfl_xor(rm, off));
            float mn = fmaxf(mrow[reg], rm);
            float al = (mrow[reg] > -INFINITY) ? __expf(mrow[reg] - mn) : 0.f;
            float rs = 0.f;
#pragma unroll
            for (int nt = 0; nt < 4; ++nt) {
                float pv = (sv[nt] > -INFINITY) ? __expf(sv[nt] - mn) : 0.f;
                p[nt][reg] = pv;
                rs += pv;
            }
#pragma unroll
            for (int off = 1; off < 16; off <<= 1) rs += __shfl_xor(rs, off);
            lrow[reg] = lrow[reg] * al + rs;
            mrow[reg] = mn;
#pragma unroll
            for (int nt = 0; nt < 4; ++nt) oacc[nt][reg] *= al;
        }

        // ---- P: C-layout -> A-layout via per-wave LDS -------------------
#pragma unroll
        for (int nt = 0; nt < 4; ++nt)
#pragma unroll
            for (int reg = 0; reg < 4; ++reg)
                Ps[w][(quad * 4 + reg) * 72 + nt * 16 + l15] = (short)f2bu(p[nt][reg]);

        bf16x8 pa[2];
#pragma unroll
        for (int ks = 0; ks < 2; ++ks)
            pa[ks] = *(const bf16x8*)&Ps[w][l15 * 72 + ks * 32 + quad * 8];

        // ---- O += P V (8 MFMAs) -----------------------------------------
#pragma unroll
        for (int ks = 0; ks < 2; ++ks)
#pragma unroll
            for (int nt = 0; nt < 4; ++nt) {
                int r = nt * 16 + l15;
                int slot = (ks * 4 + quad) ^ (r & 7);
                bf16x8 vb = *(const bf16x8*)&Vs[r * 64 + slot * 8];
                oacc[nt] = __builtin_amdgcn_mfma_f32_16x16x32_bf16(pa[ks], vb, oacc[nt], 0, 0, 0);
            }
    }

    // ---- epilogue: normalize + store bf16 -------------------------------
#pragma unroll
    for (int reg = 0; reg < 4; ++reg) {
        float inv = 1.f / lrow[reg];
        int i = q0 + w * 16 + quad * 4 + reg;
#pragma unroll
        for (int nt = 0; nt < 4; ++nt)
            CTX[qkBase + (size_t)i * D_MODEL + nt * 16 + l15] =
                (unsigned short)f2bu(oacc[nt][reg] * inv);
    }
}

// ---------------------------------------------------------------------------
extern "C" void kernel_launch(void* const* d_in, const int* in_sizes, int n_in,
                              void* d_out, int out_size, void* d_ws, size_t ws_size,
                              hipStream_t stream) {
    const float* x  = (const float*)d_in[0];
    const int* mask = (const int*)d_in[1];
    const float* wq = (const float*)d_in[2];
    const float* wk = (const float*)d_in[3];
    const float* wv = (const float*)d_in[4];
    const float* wo = (const float*)d_in[5];
    float* out = (float*)d_out;

    const size_t NE = (size_t)M_TOTAL * D_MODEL;      // 8388608
    const size_t WE = (size_t)D_MODEL * D_MODEL;      // 1048576
    unsigned short* ws  = (unsigned short*)d_ws;
    unsigned short* xb  = ws;
    unsigned short* wqb = xb + NE;
    unsigned short* wkb = wqb + WE;
    unsigned short* wvb = wkb + WE;
    unsigned short* wob = wvb + WE;
    unsigned short* Qb  = wob + WE;
    unsigned short* Kb  = Qb + NE;
    unsigned short* Vb  = Kb + NE;
    unsigned short* Vtb = Vb + NE;
    unsigned short* CTX = Vb;             // alias: V consumed by transpose first

    cast_bf16<<<(int)(NE / 4 + 255) / 256, 256, 0, stream>>>(x, xb, (int)(NE / 4));
    cast_bf16<<<(int)(WE / 4 + 255) / 256, 256, 0, stream>>>(wq, wqb, (int)(WE / 4));
    cast_bf16<<<(int)(WE / 4 + 255) / 256, 256, 0, stream>>>(wk, wkb, (int)(WE / 4));
    cast_bf16<<<(int)(WE / 4 + 255) / 256, 256, 0, stream>>>(wv, wvb, (int)(WE / 4));
    cast_bf16<<<(int)(WE / 4 + 255) / 256, 256, 0, stream>>>(wo, wob, (int)(WE / 4));

    dim3 gg(D_MODEL / 128, M_TOTAL / 128);            // (8, 64)
    gemm_bt_mfma<unsigned short><<<gg, 256, 0, stream>>>(xb, wqb, Qb, M_TOTAL, D_MODEL, D_MODEL);
    gemm_bt_mfma<unsigned short><<<gg, 256, 0, stream>>>(xb, wkb, Kb, M_TOTAL, D_MODEL, D_MODEL);
    gemm_bt_mfma<unsigned short><<<gg, 256, 0, stream>>>(xb, wvb, Vb, M_TOTAL, D_MODEL, D_MODEL);

    transpose_v<<<dim3(SEQ / 64, BATCH * N_HEADS), 256, 0, stream>>>(Vb, Vtb);

    flash_mfma<<<dim3(SEQ / 64, BATCH * N_HEADS), 256, 0, stream>>>(Qb, Kb, Vtb, mask, CTX);

    gemm_bt_mfma<float><<<gg, 256, 0, stream>>>(CTX, wob, out, M_TOTAL, D_MODEL, D_MODEL);
}

// Round 5
// 362.300 us; speedup vs baseline: 17.1028x; 1.2507x over previous
//
#include <hip/hip_runtime.h>
#include <cstdint>
#include <cstddef>

#define D_MODEL 1024
#define N_HEADS 16
#define HEAD_DIM 64
#define BATCH 4
#define SEQ 2048
#define M_TOTAL (BATCH * SEQ)   // 8192

typedef __attribute__((ext_vector_type(8))) short bf16x8;    // 8 bf16 = 4 VGPRs
typedef __attribute__((ext_vector_type(4))) float f32x4;
typedef __attribute__((ext_vector_type(16))) float f32x16;

// scale = 1/sqrt(64) * log2(e), folded into Q projection (softmax in exp2 domain)
#define Q_SCALE 0.18033688011112042f

__device__ __forceinline__ unsigned short f2bu(float f) {
    union { float f; unsigned u; } x; x.f = f;
    unsigned r = x.u + 0x7FFFu + ((x.u >> 16) & 1u);   // RNE
    return (unsigned short)(r >> 16);
}

__device__ __forceinline__ void async16(void* lds, const void* g) {
    __builtin_amdgcn_global_load_lds(
        (const __attribute__((address_space(1))) void*)g,
        (__attribute__((address_space(3))) void*)lds, 16, 0, 0);
}

// ---------------------------------------------------------------------------
// One fused fp32 -> bf16 cast for x + 4 weights (contiguous dst in ws).
// ---------------------------------------------------------------------------
__global__ __launch_bounds__(256) void cast_all(const float* __restrict__ x,
                                                const float* __restrict__ wq,
                                                const float* __restrict__ wk,
                                                const float* __restrict__ wv,
                                                const float* __restrict__ wo,
                                                unsigned short* __restrict__ dst) {
    const size_t NE = (size_t)M_TOTAL * D_MODEL;
    const size_t WE = (size_t)D_MODEL * D_MODEL;
    size_t i4 = (size_t)blockIdx.x * 256 + threadIdx.x;
    size_t e = i4 * 4;
    const float* src; size_t off;
    if (e < NE) { src = x; off = e; }
    else {
        size_t t = e - NE;
        int r = (int)(t / WE); off = t - (size_t)r * WE;
        src = (r == 0) ? wq : (r == 1) ? wk : (r == 2) ? wv : wo;
    }
    float4 v = *(const float4*)(src + off);
    ushort4 o;
    o.x = f2bu(v.x); o.y = f2bu(v.y); o.z = f2bu(v.z); o.w = f2bu(v.w);
    ((ushort4*)dst)[i4] = o;
}

// ---------------------------------------------------------------------------
// Fused Q/K/V projection: Y[M,1024] = X @ W^T for 3 weight sets in one grid.
// m97-style: 128x128 tile, BK=32, global_load_lds(16B), XOR chunk swizzle.
// Q output pre-scaled by Q_SCALE.
// ---------------------------------------------------------------------------
__global__ __launch_bounds__(256) void qkv_gemm(const unsigned short* __restrict__ X,
                                                const unsigned short* __restrict__ W0,
                                                const unsigned short* __restrict__ W1,
                                                const unsigned short* __restrict__ W2,
                                                unsigned short* __restrict__ Y0,
                                                unsigned short* __restrict__ Y1,
                                                unsigned short* __restrict__ Y2) {
    __shared__ short As[128 * 32];
    __shared__ short Bs[128 * 32];

    const int sel = blockIdx.x >> 3;
    const unsigned short* W = (sel == 0) ? W0 : (sel == 1) ? W1 : W2;
    unsigned short* Y = (sel == 0) ? Y0 : (sel == 1) ? Y1 : Y2;
    const float scl = (sel == 0) ? Q_SCALE : 1.0f;

    const int tid = threadIdx.x;
    const int w = tid >> 6, lane = tid & 63, quad = lane >> 4, l15 = lane & 15;
    const int wm = w & 1, wn = w >> 1;
    const int rowBase = blockIdx.y * 128;
    const int colBase = (blockIdx.x & 7) * 128;

    f32x4 acc[4][4];
#pragma unroll
    for (int mi = 0; mi < 4; ++mi)
#pragma unroll
        for (int ni = 0; ni < 4; ++ni)
#pragma unroll
            for (int e = 0; e < 4; ++e) acc[mi][ni][e] = 0.f;

    for (int k0 = 0; k0 < 1024; k0 += 32) {
        __syncthreads();
#pragma unroll
        for (int l = 0; l < 2; ++l) {
            int c = tid + l * 256;
            int row = c >> 2, ccs = c & 3;
            int cc = ccs ^ ((row >> 1) & 3);
            async16((char*)As + c * 16, X + (size_t)(rowBase + row) * 1024 + k0 + cc * 8);
            async16((char*)Bs + c * 16, W + (size_t)(colBase + row) * 1024 + k0 + cc * 8);
        }
        __syncthreads();

        bf16x8 a[4], b[4];
#pragma unroll
        for (int mi = 0; mi < 4; ++mi) {
            int r = wm * 64 + mi * 16 + l15;
            int slot = quad ^ ((r >> 1) & 3);
            a[mi] = *(const bf16x8*)&As[r * 32 + slot * 8];
        }
#pragma unroll
        for (int ni = 0; ni < 4; ++ni) {
            int r = wn * 64 + ni * 16 + l15;
            int slot = quad ^ ((r >> 1) & 3);
            b[ni] = *(const bf16x8*)&Bs[r * 32 + slot * 8];
        }
#pragma unroll
        for (int mi = 0; mi < 4; ++mi)
#pragma unroll
            for (int ni = 0; ni < 4; ++ni)
                acc[mi][ni] = __builtin_amdgcn_mfma_f32_16x16x32_bf16(a[mi], b[ni], acc[mi][ni], 0, 0, 0);
    }

#pragma unroll
    for (int mi = 0; mi < 4; ++mi)
#pragma unroll
        for (int ni = 0; ni < 4; ++ni)
#pragma unroll
            for (int reg = 0; reg < 4; ++reg) {
                int row = rowBase + wm * 64 + mi * 16 + quad * 4 + reg;
                int col = colBase + wn * 64 + ni * 16 + l15;
                Y[(size_t)row * 1024 + col] = f2bu(acc[mi][ni][reg] * scl);
            }
}

// ---------------------------------------------------------------------------
// Output projection: out[M,1024] = CTX @ Wo^T, fp32 out. Same structure.
// ---------------------------------------------------------------------------
__global__ __launch_bounds__(256) void out_gemm(const unsigned short* __restrict__ X,
                                                const unsigned short* __restrict__ W,
                                                float* __restrict__ Y) {
    __shared__ short As[128 * 32];
    __shared__ short Bs[128 * 32];

    const int tid = threadIdx.x;
    const int w = tid >> 6, lane = tid & 63, quad = lane >> 4, l15 = lane & 15;
    const int wm = w & 1, wn = w >> 1;
    const int rowBase = blockIdx.y * 128;
    const int colBase = blockIdx.x * 128;

    f32x4 acc[4][4];
#pragma unroll
    for (int mi = 0; mi < 4; ++mi)
#pragma unroll
        for (int ni = 0; ni < 4; ++ni)
#pragma unroll
            for (int e = 0; e < 4; ++e) acc[mi][ni][e] = 0.f;

    for (int k0 = 0; k0 < 1024; k0 += 32) {
        __syncthreads();
#pragma unroll
        for (int l = 0; l < 2; ++l) {
            int c = tid + l * 256;
            int row = c >> 2, ccs = c & 3;
            int cc = ccs ^ ((row >> 1) & 3);
            async16((char*)As + c * 16, X + (size_t)(rowBase + row) * 1024 + k0 + cc * 8);
            async16((char*)Bs + c * 16, W + (size_t)(colBase + row) * 1024 + k0 + cc * 8);
        }
        __syncthreads();

        bf16x8 a[4], b[4];
#pragma unroll
        for (int mi = 0; mi < 4; ++mi) {
            int r = wm * 64 + mi * 16 + l15;
            int slot = quad ^ ((r >> 1) & 3);
            a[mi] = *(const bf16x8*)&As[r * 32 + slot * 8];
        }
#pragma unroll
        for (int ni = 0; ni < 4; ++ni) {
            int r = wn * 64 + ni * 16 + l15;
            int slot = quad ^ ((r >> 1) & 3);
            b[ni] = *(const bf16x8*)&Bs[r * 32 + slot * 8];
        }
#pragma unroll
        for (int mi = 0; mi < 4; ++mi)
#pragma unroll
            for (int ni = 0; ni < 4; ++ni)
                acc[mi][ni] = __builtin_amdgcn_mfma_f32_16x16x32_bf16(a[mi], b[ni], acc[mi][ni], 0, 0, 0);
    }

#pragma unroll
    for (int mi = 0; mi < 4; ++mi)
#pragma unroll
        for (int ni = 0; ni < 4; ++ni)
#pragma unroll
            for (int reg = 0; reg < 4; ++reg) {
                int row = rowBase + wm * 64 + mi * 16 + quad * 4 + reg;
                int col = colBase + wn * 64 + ni * 16 + l15;
                Y[(size_t)row * 1024 + col] = acc[mi][ni][reg];
            }
}

// ---------------------------------------------------------------------------
// V[B*S, D] (head-sliced) -> Vt[bh][d][s]
// ---------------------------------------------------------------------------
__global__ __launch_bounds__(256) void transpose_v(const unsigned short* __restrict__ V,
                                                   unsigned short* __restrict__ Vt) {
    const int st = blockIdx.x;
    const int bh = blockIdx.y;
    const int b = bh >> 4, h = bh & 15;
    const int tid = threadIdx.x;
    const int s0 = st * 64;
    __shared__ unsigned short Ts[64 * 72];

#pragma unroll
    for (int l = 0; l < 2; ++l) {
        int c = tid + l * 256;
        int s = c >> 3, cc = c & 7;
        *(uint4*)&Ts[s * 72 + cc * 8] =
            *(const uint4*)&V[(size_t)(b * SEQ + s0 + s) * D_MODEL + h * HEAD_DIM + cc * 8];
    }
    __syncthreads();
#pragma unroll
    for (int l = 0; l < 2; ++l) {
        int c = tid + l * 256;
        int d = c >> 3, sc = c & 7;
        unsigned short tmp[8];
#pragma unroll
        for (int j = 0; j < 8; ++j) tmp[j] = Ts[(sc * 8 + j) * 72 + d];
        *(uint4*)&Vt[((size_t)bh * HEAD_DIM + d) * SEQ + s0 + sc * 8] = *(uint4*)tmp;
    }
}

// ---------------------------------------------------------------------------
// Flash attention, 32x32x16 MFMA, S computed TRANSPOSED (St = K Q^T):
//   St C-layout: query i = lane&31, key j = (reg,lane5) -> m/l/alpha are
//   per-lane scalars; row reductions = 31 local ops + one shfl_xor(32).
// K staged with row perm j = swapbits23(p) so P regs ARE the B-operand of
//   Ot += mfma(Vt-frag, P) (no LDS round-trip for P).
// Block = 4 waves; wave w owns q-rows q0+32w..+31 (q-tile 128). k-tile 64.
// Q pre-scaled by 0.125*log2(e) -> softmax in exp2 domain.
// Epilogue: O^T -> LDS transpose -> coalesced bf16 stores.
// CTX may alias V (flash reads Vt, which transpose_v produced from V).
// ---------------------------------------------------------------------------
__global__ __launch_bounds__(256) void flash32(const unsigned short* __restrict__ Q,
                                               const unsigned short* __restrict__ K,
                                               const unsigned short* __restrict__ Vt,
                                               const int* __restrict__ mask,
                                               unsigned short* __restrict__ CTX) {
    __shared__ short lds[9216];            // Ks[0..4095] Vs[4096..8191]; Obuf overlays all
    __shared__ float biasS[64];
    __shared__ int allokS;

    short* Ks = lds;
    short* Vs = lds + 4096;

    const int qt = 15 - (int)blockIdx.x;   // longest blocks first
    const int bh = blockIdx.y;
    const int b = bh >> 4, h = bh & 15;
    const int tid = threadIdx.x;
    const int w = tid >> 6, lane = tid & 63, l31 = lane & 31, lane5 = lane >> 5;
    const int q0 = qt * 128;

    const size_t qkBase = (size_t)b * SEQ * D_MODEL + (size_t)h * HEAD_DIM;
    const size_t vtBase = (size_t)bh * HEAD_DIM * SEQ;

    // Q fragments direct from global (one-time): B[n=i=l31][k=lane5*8+jj]
    const int iq = q0 + w * 32 + l31;      // this lane's query row
    bf16x8 qf[4];
#pragma unroll
    for (int ks = 0; ks < 4; ++ks)
        qf[ks] = *(const bf16x8*)(Q + qkBase + (size_t)iq * D_MODEL + ks * 16 + lane5 * 8);

    float mv = -INFINITY, lv = 0.f;
    f32x16 Ot[2];
#pragma unroll
    for (int dt = 0; dt < 2; ++dt)
#pragma unroll
        for (int e = 0; e < 16; ++e) Ot[dt][e] = 0.f;

    const int ktmax = 2 * qt + 1;
    for (int kt = 0; kt <= ktmax; ++kt) {
        const int k0 = kt * 64;
        __syncthreads();                   // prev tile's LDS reads done
#pragma unroll
        for (int l = 0; l < 2; ++l) {
            int c = tid + l * 256;
            int p = c >> 3, sl = c & 7;
            int cc = sl ^ (p & 7);                                  // bank swizzle
            int j = (p & 0x33) | ((p & 4) << 1) | ((p & 8) >> 1);   // swap bits 2,3
            async16((char*)Ks + c * 16, K + qkBase + (size_t)(k0 + j) * D_MODEL + cc * 8);
            async16((char*)Vs + c * 16, Vt + vtBase + (size_t)p * SEQ + k0 + cc * 8);
        }
        if (tid < 64) {                    // wave 0: padding-mask fast-path flag
            int mk = mask[b * SEQ + k0 + tid];
            biasS[tid] = mk ? 0.f : -INFINITY;
            unsigned long long bal = __ballot(mk != 0);
            if (tid == 0) allokS = (bal == ~0ull) ? 1 : 0;
        }
        __syncthreads();                   // staging visible

        if (64 * kt > q0 + 32 * w + 31) continue;   // tile fully above causal diag (wave-uniform)

        // ---- St = K Q^T (8 MFMAs) ---------------------------------------
        f32x16 St[2];
#pragma unroll
        for (int T = 0; T < 2; ++T)
#pragma unroll
            for (int e = 0; e < 16; ++e) St[T][e] = 0.f;
#pragma unroll
        for (int T = 0; T < 2; ++T)
#pragma unroll
            for (int ks = 0; ks < 4; ++ks) {
                int p = T * 32 + l31;
                int slot = (ks * 2 + lane5) ^ (p & 7);
                bf16x8 a = *(const bf16x8*)&Ks[p * 64 + slot * 8];
                St[T] = __builtin_amdgcn_mfma_f32_32x32x16_bf16(a, qf[ks], St[T], 0, 0, 0);
            }

        // ---- masking ----------------------------------------------------
        const bool partial = (k0 + 63 > q0 + 32 * w);   // wave-uniform causal check needed
        if (partial) {
#pragma unroll
            for (int T = 0; T < 2; ++T)
#pragma unroll
                for (int r = 0; r < 16; ++r) {
                    int j = k0 + 32 * T + 16 * (r >> 3) + 8 * lane5 + (r & 7);
                    if (j > iq) St[T][r] = -INFINITY;
                }
        }
        if (!allokS) {
#pragma unroll
            for (int T = 0; T < 2; ++T)
#pragma unroll
                for (int r = 0; r < 16; ++r)
                    St[T][r] += biasS[32 * T + 16 * (r >> 3) + 8 * lane5 + (r & 7)];
        }

        // ---- online softmax (per-lane state, one cross-lane step) -------
        float rm = -INFINITY;
#pragma unroll
        for (int T = 0; T < 2; ++T)
#pragma unroll
            for (int r = 0; r < 16; ++r) rm = fmaxf(rm, St[T][r]);
        rm = fmaxf(rm, __shfl_xor(rm, 32));
        float mn = fmaxf(mv, rm);
        float al = (mv > -INFINITY) ? exp2f(mv - mn) : 0.f;
        float rs = 0.f;
#pragma unroll
        for (int T = 0; T < 2; ++T)
#pragma unroll
            for (int r = 0; r < 16; ++r) {
                float pv = (St[T][r] > -INFINITY) ? exp2f(St[T][r] - mn) : 0.f;
                St[T][r] = pv;
                rs += pv;
            }
        rs += __shfl_xor(rs, 32);
        lv = lv * al + rs;
        mv = mn;
#pragma unroll
        for (int dt = 0; dt < 2; ++dt)
#pragma unroll
            for (int e = 0; e < 16; ++e) Ot[dt][e] *= al;

        // ---- pack P (regs already in B-fragment order thanks to perm) ---
        bf16x8 pf[4];
#pragma unroll
        for (int t = 0; t < 4; ++t) {
            int T = t >> 1, hb = t & 1;
#pragma unroll
            for (int jj = 0; jj < 8; ++jj)
                pf[t][jj] = (short)f2bu(St[T][hb * 8 + jj]);
        }

        // ---- Ot += V^T P^T (8 MFMAs) ------------------------------------
#pragma unroll
        for (int dt = 0; dt < 2; ++dt)
#pragma unroll
            for (int t = 0; t < 4; ++t) {
                int p = dt * 32 + l31;
                int slot = (t * 2 + lane5) ^ (p & 7);
                bf16x8 a = *(const bf16x8*)&Vs[p * 64 + slot * 8];
                Ot[dt] = __builtin_amdgcn_mfma_f32_32x32x16_bf16(a, pf[t], Ot[dt], 0, 0, 0);
            }
    }

    // ---- epilogue: normalize, transpose via LDS, coalesced store --------
    __syncthreads();                       // all waves done with Ks/Vs
    const float inv = 1.f / lv;
#pragma unroll
    for (int dt = 0; dt < 2; ++dt)
#pragma unroll
        for (int k = 0; k < 8; ++k) {
            int r0 = 2 * k;
            int d = (r0 & 3) + 4 * lane5 + 8 * (r0 >> 2) + 32 * dt;
            unsigned lo = f2bu(Ot[dt][r0] * inv);
            unsigned hi = f2bu(Ot[dt][r0 + 1] * inv);
            *(unsigned*)&lds[(w * 32 + l31) * 72 + d] = lo | (hi << 16);
        }
    __syncthreads();
#pragma unroll
    for (int k = 0; k < 4; ++k) {
        int id = tid + k * 256;
        int r = id >> 3, cc = id & 7;
        uint4 v = *(const uint4*)&lds[r * 72 + cc * 8];
        *(uint4*)(CTX + qkBase + (size_t)(q0 + r) * D_MODEL + cc * 8) = v;
    }
}

// ---------------------------------------------------------------------------
extern "C" void kernel_launch(void* const* d_in, const int* in_sizes, int n_in,
                              void* d_out, int out_size, void* d_ws, size_t ws_size,
                              hipStream_t stream) {
    const float* x  = (const float*)d_in[0];
    const int* mask = (const int*)d_in[1];
    const float* wq = (const float*)d_in[2];
    const float* wk = (const float*)d_in[3];
    const float* wv = (const float*)d_in[4];
    const float* wo = (const float*)d_in[5];
    float* out = (float*)d_out;

    const size_t NE = (size_t)M_TOTAL * D_MODEL;
    const size_t WE = (size_t)D_MODEL * D_MODEL;
    unsigned short* ws  = (unsigned short*)d_ws;
    unsigned short* xb  = ws;
    unsigned short* wqb = xb + NE;
    unsigned short* wkb = wqb + WE;
    unsigned short* wvb = wkb + WE;
    unsigned short* wob = wvb + WE;
    unsigned short* Qb  = wob + WE;
    unsigned short* Kb  = Qb + NE;
    unsigned short* Vb  = Kb + NE;
    unsigned short* Vtb = Vb + NE;
    unsigned short* CTX = Vb;             // alias: V consumed by transpose first

    cast_all<<<(int)((NE + 4 * WE) / 4 / 256), 256, 0, stream>>>(x, wq, wk, wv, wo, ws);

    qkv_gemm<<<dim3(24, M_TOTAL / 128), 256, 0, stream>>>(xb, wqb, wkb, wvb, Qb, Kb, Vb);

    transpose_v<<<dim3(SEQ / 64, BATCH * N_HEADS), 256, 0, stream>>>(Vb, Vtb);

    flash32<<<dim3(SEQ / 128, BATCH * N_HEADS), 256, 0, stream>>>(Qb, Kb, Vtb, mask, CTX);

    out_gemm<<<dim3(D_MODEL / 128, M_TOTAL / 128), 256, 0, stream>>>(CTX, wob, out);
}

// Round 6
// 316.066 us; speedup vs baseline: 19.6046x; 1.1463x over previous
//
#include <hip/hip_runtime.h>
#include <cstdint>
#include <cstddef>

#define D_MODEL 1024
#define N_HEADS 16
#define HEAD_DIM 64
#define BATCH 4
#define SEQ 2048
#define M_TOTAL (BATCH * SEQ)   // 8192

typedef __attribute__((ext_vector_type(8))) short bf16x8;    // 8 bf16 = 4 VGPRs
typedef __attribute__((ext_vector_type(4))) float f32x4;
typedef __attribute__((ext_vector_type(16))) float f32x16;

// scale = 1/sqrt(64) * log2(e), folded into Q projection (softmax in exp2 domain)
#define Q_SCALE 0.18033688011112042f

__device__ __forceinline__ unsigned short f2bu(float f) {   // RNE
    union { float f; unsigned u; } x; x.f = f;
    unsigned r = x.u + 0x7FFFu + ((x.u >> 16) & 1u);
    return (unsigned short)(r >> 16);
}
__device__ __forceinline__ unsigned short f2bu_fast(float f) {  // round-half-up (P in [0,1])
    union { float f; unsigned u; } x; x.f = f;
    return (unsigned short)((x.u + 0x8000u) >> 16);
}

__device__ __forceinline__ void async16(void* lds, const void* g) {
    __builtin_amdgcn_global_load_lds(
        (const __attribute__((address_space(1))) void*)g,
        (__attribute__((address_space(3))) void*)lds, 16, 0, 0);
}

// ---------------------------------------------------------------------------
// One fused fp32 -> bf16 cast for x + 4 weights (contiguous dst in ws).
// ---------------------------------------------------------------------------
__global__ __launch_bounds__(256) void cast_all(const float* __restrict__ x,
                                                const float* __restrict__ wq,
                                                const float* __restrict__ wk,
                                                const float* __restrict__ wv,
                                                const float* __restrict__ wo,
                                                unsigned short* __restrict__ dst) {
    const size_t NE = (size_t)M_TOTAL * D_MODEL;
    const size_t WE = (size_t)D_MODEL * D_MODEL;
    size_t i4 = (size_t)blockIdx.x * 256 + threadIdx.x;
    size_t e = i4 * 4;
    const float* src; size_t off;
    if (e < NE) { src = x; off = e; }
    else {
        size_t t = e - NE;
        int r = (int)(t / WE); off = t - (size_t)r * WE;
        src = (r == 0) ? wq : (r == 1) ? wk : (r == 2) ? wv : wo;
    }
    float4 v = *(const float4*)(src + off);
    ushort4 o;
    o.x = f2bu(v.x); o.y = f2bu(v.y); o.z = f2bu(v.z); o.w = f2bu(v.w);
    ((ushort4*)dst)[i4] = o;
}

// ---------------------------------------------------------------------------
// Fused Q/K/V projection. sel 0: Q (pre-scaled by Q_SCALE), sel 1: K,
// sel 2: V written TRANSPOSED into Vt[bh][d][s] (folds transpose_v away).
// m97-style: 128x128 tile, BK=32, global_load_lds(16B), XOR chunk swizzle.
// ---------------------------------------------------------------------------
__global__ __launch_bounds__(256) void qkv_gemm(const unsigned short* __restrict__ X,
                                                const unsigned short* __restrict__ W0,
                                                const unsigned short* __restrict__ W1,
                                                const unsigned short* __restrict__ W2,
                                                unsigned short* __restrict__ Y0,
                                                unsigned short* __restrict__ Y1,
                                                unsigned short* __restrict__ Vt) {
    __shared__ short As[128 * 32];
    __shared__ short Bs[128 * 32];

    const int sel = blockIdx.x >> 3;
    const unsigned short* W = (sel == 0) ? W0 : (sel == 1) ? W1 : W2;
    const float scl = (sel == 0) ? Q_SCALE : 1.0f;

    const int tid = threadIdx.x;
    const int w = tid >> 6, lane = tid & 63, quad = lane >> 4, l15 = lane & 15;
    const int wm = w & 1, wn = w >> 1;
    const int rowBase = blockIdx.y * 128;
    const int colBase = (blockIdx.x & 7) * 128;

    f32x4 acc[4][4];
#pragma unroll
    for (int mi = 0; mi < 4; ++mi)
#pragma unroll
        for (int ni = 0; ni < 4; ++ni)
#pragma unroll
            for (int e = 0; e < 4; ++e) acc[mi][ni][e] = 0.f;

    for (int k0 = 0; k0 < 1024; k0 += 32) {
        __syncthreads();
#pragma unroll
        for (int l = 0; l < 2; ++l) {
            int c = tid + l * 256;
            int row = c >> 2, ccs = c & 3;
            int cc = ccs ^ ((row >> 1) & 3);
            async16((char*)As + c * 16, X + (size_t)(rowBase + row) * 1024 + k0 + cc * 8);
            async16((char*)Bs + c * 16, W + (size_t)(colBase + row) * 1024 + k0 + cc * 8);
        }
        __syncthreads();

        bf16x8 a[4], b[4];
#pragma unroll
        for (int mi = 0; mi < 4; ++mi) {
            int r = wm * 64 + mi * 16 + l15;
            int slot = quad ^ ((r >> 1) & 3);
            a[mi] = *(const bf16x8*)&As[r * 32 + slot * 8];
        }
#pragma unroll
        for (int ni = 0; ni < 4; ++ni) {
            int r = wn * 64 + ni * 16 + l15;
            int slot = quad ^ ((r >> 1) & 3);
            b[ni] = *(const bf16x8*)&Bs[r * 32 + slot * 8];
        }
#pragma unroll
        for (int mi = 0; mi < 4; ++mi)
#pragma unroll
            for (int ni = 0; ni < 4; ++ni)
                acc[mi][ni] = __builtin_amdgcn_mfma_f32_16x16x32_bf16(a[mi], b[ni], acc[mi][ni], 0, 0, 0);
    }

    if (sel != 2) {
        unsigned short* Y = (sel == 0) ? Y0 : Y1;
#pragma unroll
        for (int mi = 0; mi < 4; ++mi)
#pragma unroll
            for (int ni = 0; ni < 4; ++ni)
#pragma unroll
                for (int reg = 0; reg < 4; ++reg) {
                    int row = rowBase + wm * 64 + mi * 16 + quad * 4 + reg;
                    int col = colBase + wn * 64 + ni * 16 + l15;
                    Y[(size_t)row * 1024 + col] = f2bu(acc[mi][ni][reg] * scl);
                }
    } else {
        // transposed V write: Vt[((b*16+h)*64+d)*SEQ + s], 4 consecutive s per store
#pragma unroll
        for (int mi = 0; mi < 4; ++mi) {
            int row0 = rowBase + wm * 64 + mi * 16 + quad * 4;   // reg 0 row
            int bb = row0 >> 11;
            int s0 = row0 & 2047;
#pragma unroll
            for (int ni = 0; ni < 4; ++ni) {
                int col = colBase + wn * 64 + ni * 16 + l15;
                int hh = col >> 6, dd = col & 63;
                ushort4 pk;
                pk.x = f2bu(acc[mi][ni][0]); pk.y = f2bu(acc[mi][ni][1]);
                pk.z = f2bu(acc[mi][ni][2]); pk.w = f2bu(acc[mi][ni][3]);
                *(ushort4*)(Vt + (((size_t)bb * 16 + hh) * 64 + dd) * SEQ + s0) = pk;
            }
        }
    }
}

// ---------------------------------------------------------------------------
// Output projection: out[M,1024] = CTX @ Wo^T, fp32 out.
// ---------------------------------------------------------------------------
__global__ __launch_bounds__(256) void out_gemm(const unsigned short* __restrict__ X,
                                                const unsigned short* __restrict__ W,
                                                float* __restrict__ Y) {
    __shared__ short As[128 * 32];
    __shared__ short Bs[128 * 32];

    const int tid = threadIdx.x;
    const int w = tid >> 6, lane = tid & 63, quad = lane >> 4, l15 = lane & 15;
    const int wm = w & 1, wn = w >> 1;
    const int rowBase = blockIdx.y * 128;
    const int colBase = blockIdx.x * 128;

    f32x4 acc[4][4];
#pragma unroll
    for (int mi = 0; mi < 4; ++mi)
#pragma unroll
        for (int ni = 0; ni < 4; ++ni)
#pragma unroll
            for (int e = 0; e < 4; ++e) acc[mi][ni][e] = 0.f;

    for (int k0 = 0; k0 < 1024; k0 += 32) {
        __syncthreads();
#pragma unroll
        for (int l = 0; l < 2; ++l) {
            int c = tid + l * 256;
            int row = c >> 2, ccs = c & 3;
            int cc = ccs ^ ((row >> 1) & 3);
            async16((char*)As + c * 16, X + (size_t)(rowBase + row) * 1024 + k0 + cc * 8);
            async16((char*)Bs + c * 16, W + (size_t)(colBase + row) * 1024 + k0 + cc * 8);
        }
        __syncthreads();

        bf16x8 a[4], b[4];
#pragma unroll
        for (int mi = 0; mi < 4; ++mi) {
            int r = wm * 64 + mi * 16 + l15;
            int slot = quad ^ ((r >> 1) & 3);
            a[mi] = *(const bf16x8*)&As[r * 32 + slot * 8];
        }
#pragma unroll
        for (int ni = 0; ni < 4; ++ni) {
            int r = wn * 64 + ni * 16 + l15;
            int slot = quad ^ ((r >> 1) & 3);
            b[ni] = *(const bf16x8*)&Bs[r * 32 + slot * 8];
        }
#pragma unroll
        for (int mi = 0; mi < 4; ++mi)
#pragma unroll
            for (int ni = 0; ni < 4; ++ni)
                acc[mi][ni] = __builtin_amdgcn_mfma_f32_16x16x32_bf16(a[mi], b[ni], acc[mi][ni], 0, 0, 0);
    }

#pragma unroll
    for (int mi = 0; mi < 4; ++mi)
#pragma unroll
        for (int ni = 0; ni < 4; ++ni)
#pragma unroll
            for (int reg = 0; reg < 4; ++reg) {
                int row = rowBase + wm * 64 + mi * 16 + quad * 4 + reg;
                int col = colBase + wn * 64 + ni * 16 + l15;
                Y[(size_t)row * 1024 + col] = acc[mi][ni][reg];
            }
}

// ---------------------------------------------------------------------------
// Flash attention, 32x32x16 MFMA, St = K Q^T (query = lane index -> per-lane
// softmax state). Block pid handles q-tiles {15-pid, pid} sequentially:
// exactly 34 k-tile iterations per block -> perfect load balance
// (512 blocks = 2/CU x 34 tiles). Register-prefetch double buffering:
// tile t+1 global->VGPR during compute of t, ds_write after barrier (avoids
// the global_load_lds vmcnt(0)-at-barrier drain).
// ---------------------------------------------------------------------------
__global__ __launch_bounds__(256) void flash32(const unsigned short* __restrict__ Q,
                                               const unsigned short* __restrict__ K,
                                               const unsigned short* __restrict__ Vt,
                                               const int* __restrict__ mask,
                                               unsigned short* __restrict__ CTX) {
    __shared__ short lds[9216];            // Ks[0..4095] Vs[4096..8191]; epilogue overlays all
    __shared__ float biasS[64];
    __shared__ int allokS;

    short* Ks = lds;
    short* Vs = lds + 4096;

    const int pid = blockIdx.x;            // 0..7
    const int bh = blockIdx.y;
    const int b = bh >> 4;
    const int tid = threadIdx.x;
    const int w = tid >> 6, lane = tid & 63, l31 = lane & 31, lane5 = lane >> 5;

    const size_t qkBase = (size_t)b * SEQ * D_MODEL + (size_t)(bh & 15) * HEAD_DIM;
    const size_t vtBase = (size_t)bh * HEAD_DIM * SEQ;

    // per-thread staging constants (chunk c = tid + l*256)
    int stp[2], stcc[2], stj[2];
#pragma unroll
    for (int l = 0; l < 2; ++l) {
        int c = tid + l * 256;
        int p = c >> 3, sl = c & 7;
        stp[l] = p;
        stcc[l] = sl ^ (p & 7);                                   // bank swizzle
        stj[l] = (p & 0x33) | ((p & 4) << 1) | ((p & 8) >> 1);    // swap bits 2,3
    }

    for (int phase = 0; phase < 2; ++phase) {
        const int qt = phase ? pid : 15 - pid;
        const int q0 = qt * 128;
        const int iq = q0 + w * 32 + l31;      // this lane's query row

        // Q fragments direct from global: B[n=i=l31][k=lane5*8+jj]
        bf16x8 qf[4];
#pragma unroll
        for (int ks = 0; ks < 4; ++ks)
            qf[ks] = *(const bf16x8*)(Q + qkBase + (size_t)iq * D_MODEL + ks * 16 + lane5 * 8);

        float mv = -INFINITY, lv = 0.f;
        f32x16 Ot[2];
#pragma unroll
        for (int dt = 0; dt < 2; ++dt)
#pragma unroll
            for (int e = 0; e < 16; ++e) Ot[dt][e] = 0.f;

        const int ktmax = 2 * qt + 1;

        uint4 kreg[2], vreg[2];
        int mreg;
        // prefetch tile 0
        {
            const int k0 = 0;
#pragma unroll
            for (int l = 0; l < 2; ++l) {
                kreg[l] = *(const uint4*)(K + qkBase + (size_t)(k0 + stj[l]) * D_MODEL + stcc[l] * 8);
                vreg[l] = *(const uint4*)(Vt + vtBase + (size_t)stp[l] * SEQ + k0 + stcc[l] * 8);
            }
            mreg = (tid < 64) ? mask[b * SEQ + k0 + tid] : 1;
        }

        for (int kt = 0; kt <= ktmax; ++kt) {
            const int k0 = kt * 64;
            __syncthreads();                   // LDS free (prev tile reads / epilogue done)
#pragma unroll
            for (int l = 0; l < 2; ++l) {
                int c = tid + l * 256;
                *(uint4*)((char*)Ks + c * 16) = kreg[l];
                *(uint4*)((char*)Vs + c * 16) = vreg[l];
            }
            if (tid < 64) {
                biasS[tid] = mreg ? 0.f : -INFINITY;
                unsigned long long bal = __ballot(mreg != 0);
                if (tid == 0) allokS = (bal == ~0ull) ? 1 : 0;
            }
            if (kt < ktmax) {                  // prefetch next tile (overlaps compute)
                const int kn = k0 + 64;
#pragma unroll
                for (int l = 0; l < 2; ++l) {
                    kreg[l] = *(const uint4*)(K + qkBase + (size_t)(kn + stj[l]) * D_MODEL + stcc[l] * 8);
                    vreg[l] = *(const uint4*)(Vt + vtBase + (size_t)stp[l] * SEQ + kn + stcc[l] * 8);
                }
                mreg = (tid < 64) ? mask[b * SEQ + kn + tid] : 1;
            }
            __syncthreads();                   // staged tile + mask visible

            if (64 * kt > q0 + 32 * w + 31) continue;   // wave-uniform: tile above causal diag

            // ---- St = K Q^T (8 MFMAs) -----------------------------------
            f32x16 St[2];
#pragma unroll
            for (int T = 0; T < 2; ++T)
#pragma unroll
                for (int e = 0; e < 16; ++e) St[T][e] = 0.f;
#pragma unroll
            for (int T = 0; T < 2; ++T)
#pragma unroll
                for (int ks = 0; ks < 4; ++ks) {
                    int p = T * 32 + l31;
                    int slot = (ks * 2 + lane5) ^ (p & 7);
                    bf16x8 a = *(const bf16x8*)&Ks[p * 64 + slot * 8];
                    St[T] = __builtin_amdgcn_mfma_f32_32x32x16_bf16(a, qf[ks], St[T], 0, 0, 0);
                }

            // ---- masking ------------------------------------------------
            const bool partial = (k0 + 63 > q0 + 32 * w);
            if (partial) {
#pragma unroll
                for (int T = 0; T < 2; ++T)
#pragma unroll
                    for (int r = 0; r < 16; ++r) {
                        int j = k0 + 32 * T + 16 * (r >> 3) + 8 * lane5 + (r & 7);
                        if (j > iq) St[T][r] = -INFINITY;
                    }
            }
            if (!allokS) {
#pragma unroll
                for (int T = 0; T < 2; ++T)
#pragma unroll
                    for (int r = 0; r < 16; ++r)
                        St[T][r] += biasS[32 * T + 16 * (r >> 3) + 8 * lane5 + (r & 7)];
            }

            // ---- online softmax (per-lane state, one cross-lane step) ---
            float rm = -INFINITY;
#pragma unroll
            for (int T = 0; T < 2; ++T)
#pragma unroll
                for (int r = 0; r < 16; ++r) rm = fmaxf(rm, St[T][r]);
            rm = fmaxf(rm, __shfl_xor(rm, 32));
            float mn = fmaxf(mv, rm);
            float al = (mv > -INFINITY) ? exp2f(mv - mn) : 0.f;
            float rs = 0.f;
#pragma unroll
            for (int T = 0; T < 2; ++T)
#pragma unroll
                for (int r = 0; r < 16; ++r) {
                    float pv = (St[T][r] > -INFINITY) ? exp2f(St[T][r] - mn) : 0.f;
                    St[T][r] = pv;
                    rs += pv;
                }
            rs += __shfl_xor(rs, 32);
            lv = lv * al + rs;
            mv = mn;
#pragma unroll
            for (int dt = 0; dt < 2; ++dt)
#pragma unroll
                for (int e = 0; e < 16; ++e) Ot[dt][e] *= al;

            // ---- pack P (regs already in B-fragment order) --------------
            bf16x8 pf[4];
#pragma unroll
            for (int t = 0; t < 4; ++t) {
                int T = t >> 1, hb = t & 1;
#pragma unroll
                for (int jj = 0; jj < 8; ++jj)
                    pf[t][jj] = (short)f2bu_fast(St[T][hb * 8 + jj]);
            }

            // ---- Ot += V^T P^T (8 MFMAs) --------------------------------
#pragma unroll
            for (int dt = 0; dt < 2; ++dt)
#pragma unroll
                for (int t = 0; t < 4; ++t) {
                    int p = dt * 32 + l31;
                    int slot = (t * 2 + lane5) ^ (p & 7);
                    bf16x8 a = *(const bf16x8*)&Vs[p * 64 + slot * 8];
                    Ot[dt] = __builtin_amdgcn_mfma_f32_32x32x16_bf16(a, pf[t], Ot[dt], 0, 0, 0);
                }
        }

        // ---- epilogue: normalize, transpose via LDS, coalesced store ----
        __syncthreads();                       // all waves done with Ks/Vs
        const float inv = 1.f / lv;
#pragma unroll
        for (int dt = 0; dt < 2; ++dt)
#pragma unroll
            for (int k = 0; k < 8; ++k) {
                int r0 = 2 * k;
                int d = (r0 & 3) + 4 * lane5 + 8 * (r0 >> 2) + 32 * dt;
                unsigned lo = f2bu(Ot[dt][r0] * inv);
                unsigned hi = f2bu(Ot[dt][r0 + 1] * inv);
                *(unsigned*)&lds[(w * 32 + l31) * 72 + d] = lo | (hi << 16);
            }
        __syncthreads();
#pragma unroll
        for (int k = 0; k < 4; ++k) {
            int id = tid + k * 256;
            int r = id >> 3, cc = id & 7;
            uint4 v = *(const uint4*)&lds[r * 72 + cc * 8];
            *(uint4*)(CTX + qkBase + (size_t)(q0 + r) * D_MODEL + cc * 8) = v;
        }
        // next phase's first __syncthreads protects the epilogue reads
    }
}

// ---------------------------------------------------------------------------
extern "C" void kernel_launch(void* const* d_in, const int* in_sizes, int n_in,
                              void* d_out, int out_size, void* d_ws, size_t ws_size,
                              hipStream_t stream) {
    const float* x  = (const float*)d_in[0];
    const int* mask = (const int*)d_in[1];
    const float* wq = (const float*)d_in[2];
    const float* wk = (const float*)d_in[3];
    const float* wv = (const float*)d_in[4];
    const float* wo = (const float*)d_in[5];
    float* out = (float*)d_out;

    const size_t NE = (size_t)M_TOTAL * D_MODEL;
    const size_t WE = (size_t)D_MODEL * D_MODEL;
    unsigned short* ws  = (unsigned short*)d_ws;
    unsigned short* xb  = ws;
    unsigned short* wqb = xb + NE;
    unsigned short* wkb = wqb + WE;
    unsigned short* wvb = wkb + WE;
    unsigned short* wob = wvb + WE;
    unsigned short* Qb  = wob + WE;
    unsigned short* Kb  = Qb + NE;
    unsigned short* Vtb = Kb + NE;
    unsigned short* CTX = Vtb + NE;

    cast_all<<<(int)((NE + 4 * WE) / 4 / 256), 256, 0, stream>>>(x, wq, wk, wv, wo, ws);

    qkv_gemm<<<dim3(24, M_TOTAL / 128), 256, 0, stream>>>(xb, wqb, wkb, wvb, Qb, Kb, Vtb);

    flash32<<<dim3(8, BATCH * N_HEADS), 256, 0, stream>>>(Qb, Kb, Vtb, mask, CTX);

    out_gemm<<<dim3(D_MODEL / 128, M_TOTAL / 128), 256, 0, stream>>>(CTX, wob, out);
}